// Round 1
// 252.111 us; speedup vs baseline: 1.0161x; 1.0161x over previous
//
#include <hip/hip_runtime.h>
#include <hip/hip_bf16.h>

typedef __bf16 bf16;
typedef __attribute__((ext_vector_type(8))) __bf16 bf16x8;
typedef __attribute__((ext_vector_type(4))) __bf16 bf16x4;
typedef __attribute__((ext_vector_type(4))) float f32x4;
typedef __attribute__((ext_vector_type(16))) float f32x16;

#define MFMA16(a, b, c) __builtin_amdgcn_mfma_f32_16x16x32_bf16(a, b, c, 0, 0, 0)
#define MFMA32(a, b, c) __builtin_amdgcn_mfma_f32_32x32x16_bf16(a, b, c, 0, 0, 0)

__device__ __forceinline__ void gl_lds16(const void* g, void* l) {
    __builtin_amdgcn_global_load_lds(
        (const __attribute__((address_space(1))) void*)g,
        (__attribute__((address_space(3))) void*)l, 16, 0, 0);
}

// Raw barrier: no implicit vmcnt(0) drain (that drain was the 80% stall).
// Empty asm = compiler memory fence so LDS ops are not moved across it.
#define BARRIER() do { asm volatile("" ::: "memory"); \
    __builtin_amdgcn_s_barrier(); asm volatile("" ::: "memory"); } while (0)

// Problem constants: B=4, T=2048, C=1024, H=16, D=64, P=64, S=2112
#define QSCALE 0.18033688011f
#define LOGBIAS 24.0f

// ---------------------------------------------------------------------------
// prep: unchanged — mask scan, prefix K/V cvt, fp32->bf16 precast of x and W.
// ---------------------------------------------------------------------------
__global__ __launch_bounds__(256) void prep(
    const float* __restrict__ x, const float* __restrict__ Wq,
    const float* __restrict__ Wk, const float* __restrict__ Wv,
    const float* __restrict__ Wo, const float* __restrict__ pk,
    const float* __restrict__ pv, const int* __restrict__ mask,
    bf16* __restrict__ xb, bf16* __restrict__ wb,
    bf16* __restrict__ k_ws, bf16* __restrict__ vt_ws,
    int* __restrict__ ridx, int* __restrict__ nkv)
{
    const int blk = blockIdx.x, tid = threadIdx.x;
    if (blk < 4) {
        const int b = blk, lane = tid & 63, wv = tid >> 6;
        const int* mb = mask + b * 2048;
        int loc[8], s = 0;
#pragma unroll
        for (int e = 0; e < 8; ++e) { loc[e] = (mb[tid * 8 + e] != 0); s += loc[e]; }
        int inc = s;
#pragma unroll
        for (int off = 1; off < 64; off <<= 1) {
            int t = __shfl_up(inc, off);
            if (lane >= off) inc += t;
        }
        __shared__ int wt[4];
        if (lane == 63) wt[wv] = inc;
        __syncthreads();
        int wo = 0;
        for (int w = 0; w < wv; ++w) wo += wt[w];
        int excl = wo + inc - s;
#pragma unroll
        for (int e = 0; e < 8; ++e) {
            if (loc[e]) ridx[b * 2048 + excl] = tid * 8 + e;
            excl += loc[e];
        }
        if (tid == 255) nkv[b] = 64 + wo + inc;
    } else if (blk < 260) {
        int i = (blk - 4) * 256 + tid;
        {
            int base = i * 4;
            int bh = base >> 12, rem = base & 4095;
            float4 a = *(const float4*)&pk[base];
            bf16x4 ab;
            ab[0] = (bf16)a.x; ab[1] = (bf16)a.y; ab[2] = (bf16)a.z; ab[3] = (bf16)a.w;
            *(bf16x4*)&k_ws[(size_t)bh * (2112 * 64) + rem] = ab;
        }
        {
            int bh = i >> 10, r = i & 1023;
            int d = r >> 4, sq = (r & 15) * 4;
            bf16x4 vb;
#pragma unroll
            for (int e = 0; e < 4; ++e)
                vb[e] = (bf16)pv[(size_t)bh * 4096 + (sq + e) * 64 + d];
            *(bf16x4*)&vt_ws[((size_t)bh * 64 + d) * 2112 + sq] = vb;
        }
    } else {
        int i4 = (blk - 260) * 256 + tid;
        const float* src; bf16* dst; int off;
        if (i4 < 2097152) { src = x; dst = xb; off = i4; }
        else {
            int j = i4 - 2097152;
            int sel = j >> 18;
            off = j & 262143;
            src = (sel == 0) ? Wq : (sel == 1) ? Wk : (sel == 2) ? Wv : Wo;
            dst = wb + (size_t)sel * 1048576;
        }
        float4 a = *(const float4*)&src[(size_t)off * 4];
        bf16x4 o;
        o[0] = (bf16)a.x; o[1] = (bf16)a.y; o[2] = (bf16)a.z; o[3] = (bf16)a.w;
        *(bf16x4*)&dst[(size_t)off * 4] = o;
    }
}

// ---------------------------------------------------------------------------
// Pipelined 256x128 GEMM core (T2+T3+T4+T5):
//   BK=64, 16 K-tiles, 8 waves as 4M x 2N (wave tile 64x64, frags 4x4).
//   LDS: 2 x (A 256x64 + B 128x64) bf16 = 96 KB, double-buffered.
//   Per K-tile: 2 phases x {ds_read frags | issue 3 global_load_lds prefetch
//   -> s_barrier -> 16 MFMA (setprio-wrapped) -> s_barrier}.
//   s_waitcnt vmcnt(3) ONCE per K-tile (never 0 in loop): the 3 just-issued
//   prefetch rounds stay in flight across barriers.
//   Bank-conflict-free frag reads via XOR swizzle (col16 ^= row&7), applied
//   as inverse-swizzled GLOBAL source (gl_lds dest must stay linear) +
//   swizzled ds_read address (both-sides-or-neither rule).
// Per-thread aN/bN = pre-swizzled row pointers for staging round N.
// ---------------------------------------------------------------------------
__device__ __forceinline__ void gemm_pipe_256x128(
    const bf16* a0, const bf16* a1, const bf16* a2, const bf16* a3,
    const bf16* b0, const bf16* b1,
    bf16* lds, const int wave, const int lane, f32x4 (&acc)[4][4])
{
    const int ln = lane & 15, quad = lane >> 4;
    const int wm = wave >> 1, wn = wave & 1;
    const int so = wave * 512;                     // wave's 8-row slab (elems)
    const int aBase = (wm * 64 + ln) * 64;
    const int bBase = 16384 + (wn * 64 + ln) * 64;
    const int c0 = (quad * 8) ^ ((ln & 7) << 3);   // swizzled k-chunk cols
    const int c1 = (32 + quad * 8) ^ ((ln & 7) << 3);

    // prologue: stage tile 0 into buf0 (6 rounds of 64 rows)
    gl_lds16(a0, lds + so);
    gl_lds16(a1, lds + 4096 + so);
    gl_lds16(a2, lds + 8192 + so);
    gl_lds16(a3, lds + 12288 + so);
    gl_lds16(b0, lds + 16384 + so);
    gl_lds16(b1, lds + 20480 + so);

#pragma unroll 2
    for (int t = 0; t < 16; ++t) {
        bf16* cur = lds + ((t & 1) ? 24576 : 0);
        bf16* nxt = lds + ((t & 1) ? 0 : 24576);
        const int kn = (t + 1) * 64;

        // ---- phase 0: prefetch A rounds 0-2 of next tile, wait this tile ----
        if (t < 15) {
            gl_lds16(a0 + kn, nxt + so);
            gl_lds16(a1 + kn, nxt + 4096 + so);
            gl_lds16(a2 + kn, nxt + 8192 + so);
            asm volatile("s_waitcnt vmcnt(3)" ::: "memory");  // tile t landed
        } else {
            asm volatile("s_waitcnt vmcnt(0)" ::: "memory");
        }
        BARRIER();                                  // all waves' stages visible

        bf16x8 fa[4][2], fb[2][2];
#pragma unroll
        for (int mi = 0; mi < 4; ++mi) {
            fa[mi][0] = *(const bf16x8*)(cur + aBase + mi * 1024 + c0);
            fa[mi][1] = *(const bf16x8*)(cur + aBase + mi * 1024 + c1);
        }
#pragma unroll
        for (int ni = 0; ni < 2; ++ni) {
            fb[ni][0] = *(const bf16x8*)(cur + bBase + ni * 1024 + c0);
            fb[ni][1] = *(const bf16x8*)(cur + bBase + ni * 1024 + c1);
        }
        __builtin_amdgcn_s_setprio(1);
#pragma unroll
        for (int mi = 0; mi < 4; ++mi)
#pragma unroll
            for (int ni = 0; ni < 2; ++ni) {
                acc[mi][ni] = MFMA16(fa[mi][0], fb[ni][0], acc[mi][ni]);
                acc[mi][ni] = MFMA16(fa[mi][1], fb[ni][1], acc[mi][ni]);
            }
        __builtin_amdgcn_s_setprio(0);
        BARRIER();

        // ---- phase 1: read B-half 1, prefetch rounds 3-5, MFMA ----
#pragma unroll
        for (int ni = 0; ni < 2; ++ni) {
            fb[ni][0] = *(const bf16x8*)(cur + bBase + (2 + ni) * 1024 + c0);
            fb[ni][1] = *(const bf16x8*)(cur + bBase + (2 + ni) * 1024 + c1);
        }
        if (t < 15) {
            gl_lds16(a3 + kn, nxt + 12288 + so);
            gl_lds16(b0 + kn, nxt + 16384 + so);
            gl_lds16(b1 + kn, nxt + 20480 + so);
        }
        BARRIER();
        __builtin_amdgcn_s_setprio(1);
#pragma unroll
        for (int mi = 0; mi < 4; ++mi)
#pragma unroll
            for (int ni = 0; ni < 2; ++ni) {
                acc[mi][2 + ni] = MFMA16(fa[mi][0], fb[ni][0], acc[mi][2 + ni]);
                acc[mi][2 + ni] = MFMA16(fa[mi][1], fb[ni][1], acc[mi][2 + ni]);
            }
        __builtin_amdgcn_s_setprio(0);
        BARRIER();   // all reads of cur retired before next iter overwrites it
    }
}

// ---------------------------------------------------------------------------
// Merged projection dispatch (new geometry).
// blocks [0,256): Q (m-tile-major for XCD A-panel locality);
// [256,512): K over compacted rows; [512,768): V.  768 % 8 == 0 -> simple
// XCD swizzle is bijective.
// ---------------------------------------------------------------------------
__global__ __launch_bounds__(512, 2) void proj_gemm(
    const bf16* __restrict__ X, const bf16* __restrict__ Wb,
    const float* __restrict__ bq, const float* __restrict__ bk,
    const float* __restrict__ bv, const int* __restrict__ ridx,
    const int* __restrict__ nkv,
    bf16* __restrict__ q_ws, bf16* __restrict__ k_ws, bf16* __restrict__ vt_ws)
{
    __shared__ bf16 lds[49152];
    const int hw = blockIdx.x;
    const int bx = (hw & 7) * 96 + (hw >> 3);      // XCD-aware swizzle
    const int tid = threadIdx.x, wave = tid >> 6, lane = tid & 63;
    const int sr8 = lane >> 3;
    const int csw = ((lane & 7) ^ sr8) << 3;       // inverse-swizzled src col

    int kind, m0 = 0, n0, bsel = 0, nvis = 0, mbase = 0;
    const bf16* W;
    const float* bias;
    if (bx < 256) {
        kind = 0; m0 = (bx >> 3) * 256; n0 = (bx & 7) * 128;
        W = Wb; bias = bq;
    } else {
        int j = bx - 256;
        kind = 1 + (j >> 8);
        int r = j & 255;
        bsel = r >> 6;
        int rr = r & 63;
        mbase = (rr >> 3) * 256;
        n0 = (rr & 7) * 128;
        nvis = nkv[bsel] - 64;
        if (mbase >= nvis) return;
        W = Wb + (size_t)kind * 1048576;
        bias = (kind == 1) ? bk : bv;
    }

    // per-thread staging row pointers (4 A rounds, 2 B rounds)
    const bf16 *a0, *a1, *a2, *a3;
    if (kind == 0) {
        a0 = X + (size_t)(m0 + wave * 8 + sr8) * 1024 + csw;
        a1 = a0 + (size_t)64 * 1024;
        a2 = a0 + (size_t)128 * 1024;
        a3 = a0 + (size_t)192 * 1024;
    } else {
        const int* rb = ridx + bsel * 2048;
        const int nv1 = nvis - 1;
        int g = mbase + wave * 8 + sr8;
        int e0 = (g       < nv1) ? g       : nv1;
        int e1 = (g + 64  < nv1) ? g + 64  : nv1;
        int e2 = (g + 128 < nv1) ? g + 128 : nv1;
        int e3 = (g + 192 < nv1) ? g + 192 : nv1;
        const bf16* Xb = X + (size_t)bsel * 2048 * 1024 + csw;
        a0 = Xb + (size_t)rb[e0] * 1024;
        a1 = Xb + (size_t)rb[e1] * 1024;
        a2 = Xb + (size_t)rb[e2] * 1024;
        a3 = Xb + (size_t)rb[e3] * 1024;
    }
    const bf16* b0 = W + (size_t)(n0 + wave * 8 + sr8) * 1024 + csw;
    const bf16* b1 = b0 + (size_t)64 * 1024;

    const f32x4 z4 = {0.f, 0.f, 0.f, 0.f};
    f32x4 acc[4][4];
#pragma unroll
    for (int i = 0; i < 4; ++i)
#pragma unroll
        for (int j = 0; j < 4; ++j) acc[i][j] = z4;

    gemm_pipe_256x128(a0, a1, a2, a3, b0, b1, lds, wave, lane, acc);

    // epilogue: m = m0|mbase + wm*64 + mi*16 + quad*4 + r ;
    //           n = n0 + wn*64 + ni*16 + ln
    const int ln = lane & 15, quad = lane >> 4;
    const int wm = wave >> 1, wn = wave & 1;
    if (kind == 0) {
#pragma unroll
        for (int ni = 0; ni < 4; ++ni) {
            const int n = n0 + wn * 64 + ni * 16 + ln;
            const float bb = bias[n];
            const int h = n >> 6, d = n & 63;
#pragma unroll
            for (int mi = 0; mi < 4; ++mi) {
                int m = m0 + wm * 64 + mi * 16 + quad * 4;
                int b = m >> 11, tq = m & 2047;
#pragma unroll
                for (int r = 0; r < 4; ++r)
                    q_ws[((size_t)(b * 16 + h) * 2048 + tq + r) * 64 + d] =
                        (bf16)((acc[mi][ni][r] + bb) * QSCALE);
            }
        }
    } else {
#pragma unroll
        for (int ni = 0; ni < 4; ++ni) {
            const int n = n0 + wn * 64 + ni * 16 + ln;
            const float bb = bias[n];
            const int h = n >> 6, d = n & 63;
            const size_t bh64 = (size_t)(bsel * 16 + h);
#pragma unroll
            for (int mi = 0; mi < 4; ++mi) {
                int ml = mbase + wm * 64 + mi * 16 + quad * 4;
                if (kind == 1) {
#pragma unroll
                    for (int r = 0; r < 4; ++r)
                        if (ml + r < nvis)
                            k_ws[(bh64 * 2112 + 64 + ml + r) * 64 + d] =
                                (bf16)(acc[mi][ni][r] + bb);
                } else {
                    if (ml + 3 < nvis) {
                        bf16x4 pb;
#pragma unroll
                        for (int r = 0; r < 4; ++r) pb[r] = (bf16)(acc[mi][ni][r] + bb);
                        *(bf16x4*)&vt_ws[(bh64 * 64 + d) * 2112 + 64 + ml] = pb;
                    } else {
#pragma unroll
                        for (int r = 0; r < 4; ++r)
                            if (ml + r < nvis)
                                vt_ws[(bh64 * 64 + d) * 2112 + 64 + ml + r] =
                                    (bf16)(acc[mi][ni][r] + bb);
                    }
                }
            }
        }
    }
}

// ---------------------------------------------------------------------------
// Flash attention v3: unchanged.
// ---------------------------------------------------------------------------
__global__ __launch_bounds__(256) void attn_kernel(
    const bf16* __restrict__ Q, const bf16* __restrict__ K,
    const bf16* __restrict__ VT, const int* __restrict__ nk,
    bf16* __restrict__ O)
{
    __shared__ bf16 smem[128 * 72];
    bf16* Ks = smem;               // [s][d] rows 0..63, stride 72
    bf16* Vt = smem + 64 * 72;     // [d][s-permuted] rows 0..63, stride 72
    const int tid = threadIdx.x, wave = tid >> 6, lane = tid & 63;
    const int ln = lane & 31, hh = lane >> 5;
    const int bh = blockIdx.y, b = bh >> 4, head = bh & 15;
    const bf16* __restrict__ Kb  = K  + (size_t)bh * (2112 * 64);
    const bf16* __restrict__ Vtb = VT + (size_t)bh * (64 * 2112);
    const int qg = blockIdx.x * 128 + wave * 32 + ln;
    const int nkeys = nk[b];
    const int send = ((nkeys + 63) >> 6) << 6;

    bf16x8 qf[4];
#pragma unroll
    for (int kt = 0; kt < 4; ++kt)
        qf[kt] = *(const bf16x8*)&Q[((size_t)bh * 2048 + qg) * 64 + kt * 16 + hh * 8];

    float l_r = 0.f;
    f32x16 acc[2];
#pragma unroll
    for (int r = 0; r < 16; ++r) { acc[0][r] = 0.f; acc[1][r] = 0.f; }

    const int ks_s = tid >> 3, ks_c = (tid & 7) * 8;
    const int vd = tid >> 3, v8 = tid & 7, vs = v8 * 8;
    const int vcb = (v8 >> 1) * 16 + ((v8 & 1) ? 4 : 0);   // permuted col base

    bf16x8 kr0, kr1, vr0, vr1;
    kr0 = *(const bf16x8*)&Kb[(size_t)ks_s * 64 + ks_c];
    kr1 = *(const bf16x8*)&Kb[(size_t)(ks_s + 32) * 64 + ks_c];
    vr0 = *(const bf16x8*)&Vtb[(size_t)vd * 2112 + vs];
    vr1 = *(const bf16x8*)&Vtb[(size_t)(vd + 32) * 2112 + vs];

    for (int s0 = 0; s0 < send; s0 += 64) {
        __syncthreads();
        *(bf16x8*)&Ks[ks_s * 72 + ks_c]        = kr0;
        *(bf16x8*)&Ks[(ks_s + 32) * 72 + ks_c] = kr1;
        {
            bf16x4 lo, hi;
#pragma unroll
            for (int e = 0; e < 4; ++e) { lo[e] = vr0[e]; hi[e] = vr0[4 + e]; }
            *(bf16x4*)&Vt[vd * 72 + vcb]     = lo;
            *(bf16x4*)&Vt[vd * 72 + vcb + 8] = hi;
#pragma unroll
            for (int e = 0; e < 4; ++e) { lo[e] = vr1[e]; hi[e] = vr1[4 + e]; }
            *(bf16x4*)&Vt[(vd + 32) * 72 + vcb]     = lo;
            *(bf16x4*)&Vt[(vd + 32) * 72 + vcb + 8] = hi;
        }
        __syncthreads();

        if (s0 + 64 < send) {
            const int sn = s0 + 64;
            kr0 = *(const bf16x8*)&Kb[(size_t)(sn + ks_s) * 64 + ks_c];
            kr1 = *(const bf16x8*)&Kb[(size_t)(sn + ks_s + 32) * 64 + ks_c];
            vr0 = *(const bf16x8*)&Vtb[(size_t)vd * 2112 + sn + vs];
            vr1 = *(const bf16x8*)&Vtb[(size_t)(vd + 32) * 2112 + sn + vs];
        }

        // ---- S^T = K * Q^T ----
        f32x16 sc[2];
#pragma unroll
        for (int ts = 0; ts < 2; ++ts) {
            f32x16 s16;
#pragma unroll
            for (int r = 0; r < 16; ++r) s16[r] = 0.f;
#pragma unroll
            for (int kt = 0; kt < 4; ++kt) {
                bf16x8 kf = *(const bf16x8*)&Ks[(ts * 32 + ln) * 72 + kt * 16 + hh * 8];
                s16 = MFMA32(kf, qf[kt], s16);
            }
            sc[ts] = s16;
        }

        // ---- exp2 + pack P into register B-fragments (sigma order) ----
        float rs = 0.f;
        bf16x8 pf[4];
        if (s0 + 64 <= nkeys) {
#pragma unroll
            for (int ts = 0; ts < 2; ++ts)
#pragma unroll
                for (int rg = 0; rg < 4; ++rg)
#pragma unroll
                    for (int i = 0; i < 4; ++i) {
                        float p = __builtin_amdgcn_exp2f(sc[ts][rg * 4 + i] - LOGBIAS);
                        rs += p;
                        pf[ts * 2 + (rg >> 1)][(rg & 1) * 4 + i] = (bf16)p;
                    }
        } else {
#pragma unroll
            for (int ts = 0; ts < 2; ++ts)
#pragma unroll
                for (int rg = 0; rg < 4; ++rg)
#pragma unroll
                    for (int i = 0; i < 4; ++i) {
                        int key = s0 + ts * 32 + rg * 8 + hh * 4 + i;
                        float add = (key < nkeys) ? -LOGBIAS : -1e30f;
                        float p = __builtin_amdgcn_exp2f(sc[ts][rg * 4 + i] + add);
                        rs += p;
                        pf[ts * 2 + (rg >> 1)][(rg & 1) * 4 + i] = (bf16)p;
                    }
        }
        l_r += rs;

        // ---- O^T += V^T * P (permuted k) ----
#pragma unroll
        for (int st = 0; st < 4; ++st) {
            bf16x8 a0 = *(const bf16x8*)&Vt[ln * 72 + st * 16 + hh * 8];
            acc[0] = MFMA32(a0, pf[st], acc[0]);
            bf16x8 a1 = *(const bf16x8*)&Vt[(32 + ln) * 72 + st * 16 + hh * 8];
            acc[1] = MFMA32(a1, pf[st], acc[1]);
        }
    }

    // ---- epilogue: normalize, transpose via smem scratch, store ----
    __syncthreads();                 // all waves done with Ks/Vt
    l_r += __shfl_xor(l_r, 32);
    float inv = 1.0f / l_r;
    bf16* scratch = smem + wave * (32 * 72);
#pragma unroll
    for (int td = 0; td < 2; ++td)
#pragma unroll
        for (int rg = 0; rg < 4; ++rg) {
            bf16x4 ob;
#pragma unroll
            for (int i = 0; i < 4; ++i) ob[i] = (bf16)(acc[td][rg * 4 + i] * inv);
            *(bf16x4*)&scratch[ln * 72 + td * 32 + rg * 8 + hh * 4] = ob;
        }
    __builtin_amdgcn_s_waitcnt(0xC07F);   // lgkmcnt(0): own-wave scratch visible
    const int orow = lane >> 3, oc = (lane & 7) * 8;
#pragma unroll
    for (int pass = 0; pass < 4; ++pass) {
        int ml = pass * 8 + orow;
        bf16x8 ov = *(const bf16x8*)&scratch[ml * 72 + oc];
        int qrow = blockIdx.x * 128 + wave * 32 + ml;
        *(bf16x8*)&O[((size_t)b * 2048 + qrow) * 1024 + head * 64 + oc] = ov;
    }
}

// ---------------------------------------------------------------------------
// Output projection: same pipelined 256x128 core; fp32 out + bias.
// ---------------------------------------------------------------------------
__global__ __launch_bounds__(512, 2) void out_proj_gemm(
    const bf16* __restrict__ A, const bf16* __restrict__ W,
    const float* __restrict__ bias, float* __restrict__ out)
{
    __shared__ bf16 lds[49152];
    const int hw = blockIdx.x;
    const int bx = (hw & 7) * 32 + (hw >> 3);      // 256 % 8 == 0: bijective
    const int m0 = (bx >> 3) * 256, n0 = (bx & 7) * 128;
    const int tid = threadIdx.x, wave = tid >> 6, lane = tid & 63;
    const int sr8 = lane >> 3;
    const int csw = ((lane & 7) ^ sr8) << 3;

    const bf16* a0 = A + (size_t)(m0 + wave * 8 + sr8) * 1024 + csw;
    const bf16* a1 = a0 + (size_t)64 * 1024;
    const bf16* a2 = a0 + (size_t)128 * 1024;
    const bf16* a3 = a0 + (size_t)192 * 1024;
    const bf16* b0 = W + (size_t)(n0 + wave * 8 + sr8) * 1024 + csw;
    const bf16* b1 = b0 + (size_t)64 * 1024;

    const f32x4 z4 = {0.f, 0.f, 0.f, 0.f};
    f32x4 acc[4][4];
#pragma unroll
    for (int i = 0; i < 4; ++i)
#pragma unroll
        for (int j = 0; j < 4; ++j) acc[i][j] = z4;

    gemm_pipe_256x128(a0, a1, a2, a3, b0, b1, lds, wave, lane, acc);

    const int ln = lane & 15, quad = lane >> 4;
    const int wm = wave >> 1, wn = wave & 1;
#pragma unroll
    for (int ni = 0; ni < 4; ++ni) {
        const int n = n0 + wn * 64 + ni * 16 + ln;
        const float bb = bias[n];
#pragma unroll
        for (int mi = 0; mi < 4; ++mi) {
            int m = m0 + wm * 64 + mi * 16 + quad * 4;
#pragma unroll
            for (int r = 0; r < 4; ++r)
                out[(size_t)(m + r) * 1024 + n] = acc[mi][ni][r] + bb;
        }
    }
}

// ---------------------------------------------------------------------------
extern "C" void kernel_launch(void* const* d_in, const int* in_sizes, int n_in,
                              void* d_out, int out_size, void* d_ws, size_t ws_size,
                              hipStream_t stream)
{
    const float* x    = (const float*)d_in[0];
    const int*   mask = (const int*)d_in[1];
    const float* pk   = (const float*)d_in[2];
    const float* pv   = (const float*)d_in[3];
    const float* Wq   = (const float*)d_in[4];
    const float* bq   = (const float*)d_in[5];
    const float* Wk   = (const float*)d_in[6];
    const float* bk   = (const float*)d_in[7];
    const float* Wv   = (const float*)d_in[8];
    const float* bv   = (const float*)d_in[9];
    const float* Wo   = (const float*)d_in[10];
    const float* bo   = (const float*)d_in[11];
    float* out = (float*)d_out;

    bf16* xb    = (bf16*)d_ws;                   // [8192,1024] bf16
    bf16* wb    = xb + (size_t)8388608;          // 4 x [1024,1024] bf16
    bf16* q_ws  = wb + (size_t)4194304;          // [B,H,T,D]
    bf16* k_ws  = q_ws + (size_t)8388608;        // [B,H,S,D] compacted
    bf16* vt_ws = k_ws + (size_t)8650752;        // [B,H,D,S] compacted V^T
    int*  ridx  = (int*)(vt_ws + (size_t)8650752);  // [B,T]
    int*  nkv   = ridx + 4 * 2048;                  // [B]
    bf16* a_ws  = xb;   // alias: xb consumed by projections before attn writes

    prep<<<dim3(12548), 256, 0, stream>>>(x, Wq, Wk, Wv, Wo, pk, pv, mask,
                                          xb, wb, k_ws, vt_ws, ridx, nkv);
    proj_gemm<<<dim3(768), 512, 0, stream>>>(xb, wb, bq, bk, bv, ridx, nkv,
                                             q_ws, k_ws, vt_ws);
    attn_kernel<<<dim3(16, 64), 256, 0, stream>>>(q_ws, k_ws, vt_ws, nkv, a_ws);
    out_proj_gemm<<<dim3(256), 512, 0, stream>>>(a_ws, wb + (size_t)3 * 1048576,
                                                 bo, out);
}

// Round 2
// 231.728 us; speedup vs baseline: 1.1055x; 1.0880x over previous
//
#include <hip/hip_runtime.h>
#include <hip/hip_bf16.h>

typedef __bf16 bf16;
typedef __attribute__((ext_vector_type(8))) __bf16 bf16x8;
typedef __attribute__((ext_vector_type(4))) __bf16 bf16x4;
typedef __attribute__((ext_vector_type(4))) float f32x4;
typedef __attribute__((ext_vector_type(16))) float f32x16;

#define MFMA16(a, b, c) __builtin_amdgcn_mfma_f32_16x16x32_bf16(a, b, c, 0, 0, 0)
#define MFMA32(a, b, c) __builtin_amdgcn_mfma_f32_32x32x16_bf16(a, b, c, 0, 0, 0)

__device__ __forceinline__ void gl_lds16(const void* g, void* l) {
    __builtin_amdgcn_global_load_lds(
        (const __attribute__((address_space(1))) void*)g,
        (__attribute__((address_space(3))) void*)l, 16, 0, 0);
}

// Raw barrier: no implicit vmcnt(0) drain.
#define BARRIER() do { asm volatile("" ::: "memory"); \
    __builtin_amdgcn_s_barrier(); asm volatile("" ::: "memory"); } while (0)

// Problem constants: B=4, T=2048, C=1024, H=16, D=64, P=64, S=2112
#define QSCALE 0.18033688011f
#define LOGBIAS 24.0f

// sigma: V column permutation within each 64-key tile (makes PV's B-fragment
// the lane's own packed P regs).  sigma(c) = (c>>4)<<4 | ((c>>3)&1)*4 |
// ((c&4)?8:0) | (c&3).  Now baked into vt_ws GLOBAL layout by the producers
// (prep prefix-V, proj_gemm V-epilogue) so attn stages V with plain b128 ops.
__device__ __forceinline__ int vsig4(int c) {   // c % 4 == 0 fast path (base)
    return ((c >> 4) << 4) + (((c >> 3) & 1) << 2) + ((c & 4) ? 8 : 0);
}

// ---------------------------------------------------------------------------
// prep: (a) per-batch mask scan, (b) prefix K/V cvt (V^T sigma-permuted),
// (c) fp32->bf16 precast of x and W (bf16x8-wide).
// ---------------------------------------------------------------------------
__global__ __launch_bounds__(256) void prep(
    const float* __restrict__ x, const float* __restrict__ Wq,
    const float* __restrict__ Wk, const float* __restrict__ Wv,
    const float* __restrict__ Wo, const float* __restrict__ pk,
    const float* __restrict__ pv, const int* __restrict__ mask,
    bf16* __restrict__ xb, bf16* __restrict__ wb,
    bf16* __restrict__ k_ws, bf16* __restrict__ vt_ws,
    int* __restrict__ ridx, int* __restrict__ nkv)
{
    const int blk = blockIdx.x, tid = threadIdx.x;
    if (blk < 4) {
        const int b = blk, lane = tid & 63, wv = tid >> 6;
        const int* mb = mask + b * 2048;
        int loc[8], s = 0;
#pragma unroll
        for (int e = 0; e < 8; ++e) { loc[e] = (mb[tid * 8 + e] != 0); s += loc[e]; }
        int inc = s;
#pragma unroll
        for (int off = 1; off < 64; off <<= 1) {
            int t = __shfl_up(inc, off);
            if (lane >= off) inc += t;
        }
        __shared__ int wt[4];
        if (lane == 63) wt[wv] = inc;
        __syncthreads();
        int wo = 0;
        for (int w = 0; w < wv; ++w) wo += wt[w];
        int excl = wo + inc - s;
#pragma unroll
        for (int e = 0; e < 8; ++e) {
            if (loc[e]) ridx[b * 2048 + excl] = tid * 8 + e;
            excl += loc[e];
        }
        if (tid == 255) nkv[b] = 64 + wo + inc;
    } else if (blk < 260) {
        int i = (blk - 4) * 256 + tid;
        {
            int base = i * 4;
            int bh = base >> 12, rem = base & 4095;
            float4 a = *(const float4*)&pk[base];
            bf16x4 ab;
            ab[0] = (bf16)a.x; ab[1] = (bf16)a.y; ab[2] = (bf16)a.z; ab[3] = (bf16)a.w;
            *(bf16x4*)&k_ws[(size_t)bh * (2112 * 64) + rem] = ab;
        }
        {
            int bh = i >> 10, r = i & 1023;
            int d = r >> 4, sq = (r & 15) * 4;
            bf16x4 vb;
#pragma unroll
            for (int e = 0; e < 4; ++e)
                vb[e] = (bf16)pv[(size_t)bh * 4096 + (sq + e) * 64 + d];
            *(bf16x4*)&vt_ws[((size_t)bh * 64 + d) * 2112 + vsig4(sq)] = vb;
        }
    } else {
        int i8 = (blk - 260) * 256 + tid;   // 8-elem (bf16x8) units
        const float* src; bf16* dst; size_t off;
        if (i8 < 1048576) { src = x; dst = xb; off = (size_t)i8; }
        else {
            int j = i8 - 1048576;
            int sel = j >> 17;
            off = (size_t)(j & 131071);
            src = (sel == 0) ? Wq : (sel == 1) ? Wk : (sel == 2) ? Wv : Wo;
            dst = wb + (size_t)sel * 1048576;
        }
        float4 a = *(const float4*)&src[off * 8];
        float4 c = *(const float4*)&src[off * 8 + 4];
        bf16x8 o;
        o[0] = (bf16)a.x; o[1] = (bf16)a.y; o[2] = (bf16)a.z; o[3] = (bf16)a.w;
        o[4] = (bf16)c.x; o[5] = (bf16)c.y; o[6] = (bf16)c.z; o[7] = (bf16)c.w;
        *(bf16x8*)&dst[off * 8] = o;
    }
}

// ---------------------------------------------------------------------------
// Pipelined 256x128 GEMM core (T2+T3+T4+T5) — unchanged from round 1.
// ---------------------------------------------------------------------------
__device__ __forceinline__ void gemm_pipe_256x128(
    const bf16* a0, const bf16* a1, const bf16* a2, const bf16* a3,
    const bf16* b0, const bf16* b1,
    bf16* lds, const int wave, const int lane, f32x4 (&acc)[4][4])
{
    const int ln = lane & 15, quad = lane >> 4;
    const int wm = wave >> 1, wn = wave & 1;
    const int so = wave * 512;
    const int aBase = (wm * 64 + ln) * 64;
    const int bBase = 16384 + (wn * 64 + ln) * 64;
    const int c0 = (quad * 8) ^ ((ln & 7) << 3);
    const int c1 = (32 + quad * 8) ^ ((ln & 7) << 3);

    gl_lds16(a0, lds + so);
    gl_lds16(a1, lds + 4096 + so);
    gl_lds16(a2, lds + 8192 + so);
    gl_lds16(a3, lds + 12288 + so);
    gl_lds16(b0, lds + 16384 + so);
    gl_lds16(b1, lds + 20480 + so);

#pragma unroll 2
    for (int t = 0; t < 16; ++t) {
        bf16* cur = lds + ((t & 1) ? 24576 : 0);
        bf16* nxt = lds + ((t & 1) ? 0 : 24576);
        const int kn = (t + 1) * 64;

        if (t < 15) {
            gl_lds16(a0 + kn, nxt + so);
            gl_lds16(a1 + kn, nxt + 4096 + so);
            gl_lds16(a2 + kn, nxt + 8192 + so);
            asm volatile("s_waitcnt vmcnt(3)" ::: "memory");
        } else {
            asm volatile("s_waitcnt vmcnt(0)" ::: "memory");
        }
        BARRIER();

        bf16x8 fa[4][2], fb[2][2];
#pragma unroll
        for (int mi = 0; mi < 4; ++mi) {
            fa[mi][0] = *(const bf16x8*)(cur + aBase + mi * 1024 + c0);
            fa[mi][1] = *(const bf16x8*)(cur + aBase + mi * 1024 + c1);
        }
#pragma unroll
        for (int ni = 0; ni < 2; ++ni) {
            fb[ni][0] = *(const bf16x8*)(cur + bBase + ni * 1024 + c0);
            fb[ni][1] = *(const bf16x8*)(cur + bBase + ni * 1024 + c1);
        }
        __builtin_amdgcn_s_setprio(1);
#pragma unroll
        for (int mi = 0; mi < 4; ++mi)
#pragma unroll
            for (int ni = 0; ni < 2; ++ni) {
                acc[mi][ni] = MFMA16(fa[mi][0], fb[ni][0], acc[mi][ni]);
                acc[mi][ni] = MFMA16(fa[mi][1], fb[ni][1], acc[mi][ni]);
            }
        __builtin_amdgcn_s_setprio(0);
        BARRIER();

#pragma unroll
        for (int ni = 0; ni < 2; ++ni) {
            fb[ni][0] = *(const bf16x8*)(cur + bBase + (2 + ni) * 1024 + c0);
            fb[ni][1] = *(const bf16x8*)(cur + bBase + (2 + ni) * 1024 + c1);
        }
        if (t < 15) {
            gl_lds16(a3 + kn, nxt + 12288 + so);
            gl_lds16(b0 + kn, nxt + 16384 + so);
            gl_lds16(b1 + kn, nxt + 20480 + so);
        }
        BARRIER();
        __builtin_amdgcn_s_setprio(1);
#pragma unroll
        for (int mi = 0; mi < 4; ++mi)
#pragma unroll
            for (int ni = 0; ni < 2; ++ni) {
                acc[mi][2 + ni] = MFMA16(fa[mi][0], fb[ni][0], acc[mi][2 + ni]);
                acc[mi][2 + ni] = MFMA16(fa[mi][1], fb[ni][1], acc[mi][2 + ni]);
            }
        __builtin_amdgcn_s_setprio(0);
        BARRIER();
    }
}

// ---------------------------------------------------------------------------
// Merged projection dispatch.  V epilogue now writes sigma-permuted columns.
// ---------------------------------------------------------------------------
__global__ __launch_bounds__(512, 2) void proj_gemm(
    const bf16* __restrict__ X, const bf16* __restrict__ Wb,
    const float* __restrict__ bq, const float* __restrict__ bk,
    const float* __restrict__ bv, const int* __restrict__ ridx,
    const int* __restrict__ nkv,
    bf16* __restrict__ q_ws, bf16* __restrict__ k_ws, bf16* __restrict__ vt_ws)
{
    __shared__ bf16 lds[49152];
    const int hw = blockIdx.x;
    const int bx = (hw & 7) * 96 + (hw >> 3);      // XCD-aware swizzle
    const int tid = threadIdx.x, wave = tid >> 6, lane = tid & 63;
    const int sr8 = lane >> 3;
    const int csw = ((lane & 7) ^ sr8) << 3;

    int kind, m0 = 0, n0, bsel = 0, nvis = 0, mbase = 0;
    const bf16* W;
    const float* bias;
    if (bx < 256) {
        kind = 0; m0 = (bx >> 3) * 256; n0 = (bx & 7) * 128;
        W = Wb; bias = bq;
    } else {
        int j = bx - 256;
        kind = 1 + (j >> 8);
        int r = j & 255;
        bsel = r >> 6;
        int rr = r & 63;
        mbase = (rr >> 3) * 256;
        n0 = (rr & 7) * 128;
        nvis = nkv[bsel] - 64;
        if (mbase >= nvis) return;
        W = Wb + (size_t)kind * 1048576;
        bias = (kind == 1) ? bk : bv;
    }

    const bf16 *a0, *a1, *a2, *a3;
    if (kind == 0) {
        a0 = X + (size_t)(m0 + wave * 8 + sr8) * 1024 + csw;
        a1 = a0 + (size_t)64 * 1024;
        a2 = a0 + (size_t)128 * 1024;
        a3 = a0 + (size_t)192 * 1024;
    } else {
        const int* rb = ridx + bsel * 2048;
        const int nv1 = nvis - 1;
        int g = mbase + wave * 8 + sr8;
        int e0 = (g       < nv1) ? g       : nv1;
        int e1 = (g + 64  < nv1) ? g + 64  : nv1;
        int e2 = (g + 128 < nv1) ? g + 128 : nv1;
        int e3 = (g + 192 < nv1) ? g + 192 : nv1;
        const bf16* Xb = X + (size_t)bsel * 2048 * 1024 + csw;
        a0 = Xb + (size_t)rb[e0] * 1024;
        a1 = Xb + (size_t)rb[e1] * 1024;
        a2 = Xb + (size_t)rb[e2] * 1024;
        a3 = Xb + (size_t)rb[e3] * 1024;
    }
    const bf16* b0 = W + (size_t)(n0 + wave * 8 + sr8) * 1024 + csw;
    const bf16* b1 = b0 + (size_t)64 * 1024;

    const f32x4 z4 = {0.f, 0.f, 0.f, 0.f};
    f32x4 acc[4][4];
#pragma unroll
    for (int i = 0; i < 4; ++i)
#pragma unroll
        for (int j = 0; j < 4; ++j) acc[i][j] = z4;

    gemm_pipe_256x128(a0, a1, a2, a3, b0, b1, lds, wave, lane, acc);

    const int ln = lane & 15, quad = lane >> 4;
    const int wm = wave >> 1, wn = wave & 1;
    if (kind == 0) {
#pragma unroll
        for (int ni = 0; ni < 4; ++ni) {
            const int n = n0 + wn * 64 + ni * 16 + ln;
            const float bb = bias[n];
            const int h = n >> 6, d = n & 63;
#pragma unroll
            for (int mi = 0; mi < 4; ++mi) {
                int m = m0 + wm * 64 + mi * 16 + quad * 4;
                int b = m >> 11, tq = m & 2047;
#pragma unroll
                for (int r = 0; r < 4; ++r)
                    q_ws[((size_t)(b * 16 + h) * 2048 + tq + r) * 64 + d] =
                        (bf16)((acc[mi][ni][r] + bb) * QSCALE);
            }
        }
    } else {
#pragma unroll
        for (int ni = 0; ni < 4; ++ni) {
            const int n = n0 + wn * 64 + ni * 16 + ln;
            const float bb = bias[n];
            const int h = n >> 6, d = n & 63;
            const size_t bh64 = (size_t)(bsel * 16 + h);
#pragma unroll
            for (int mi = 0; mi < 4; ++mi) {
                int ml = mbase + wm * 64 + mi * 16 + quad * 4;
                if (kind == 1) {
#pragma unroll
                    for (int r = 0; r < 4; ++r)
                        if (ml + r < nvis)
                            k_ws[(bh64 * 2112 + 64 + ml + r) * 64 + d] =
                                (bf16)(acc[mi][ni][r] + bb);
                } else {
                    int g0 = 64 + ml;            // global V col, %4 == 0
                    int c0 = g0 & 63;
                    int gcol = (g0 & ~63) + vsig4(c0);
                    if (ml + 3 < nvis) {
                        bf16x4 pb;
#pragma unroll
                        for (int r = 0; r < 4; ++r) pb[r] = (bf16)(acc[mi][ni][r] + bb);
                        *(bf16x4*)&vt_ws[(bh64 * 64 + d) * 2112 + gcol] = pb;
                    } else {
#pragma unroll
                        for (int r = 0; r < 4; ++r)
                            if (ml + r < nvis)
                                vt_ws[(bh64 * 64 + d) * 2112 + gcol + r] =
                                    (bf16)(acc[mi][ni][r] + bb);
                    }
                }
            }
        }
    }
}

// ---------------------------------------------------------------------------
// Flash attention v4: 64 q-rows per wave (two 32-q groups sharing every K/V
// LDS fragment read), bias folded into the MFMA C-seed (m24), V already
// sigma-permuted in global memory (b128 staging, no repack), XCD-grouped
// block mapping (each XCD owns 8 whole (b,h) pairs -> K/V fits its L2).
// Grid: 512 blocks x 256 threads (2 blocks/CU).
// ---------------------------------------------------------------------------
__global__ __launch_bounds__(256, 2) void attn_kernel(
    const bf16* __restrict__ Q, const bf16* __restrict__ K,
    const bf16* __restrict__ VT, const int* __restrict__ nk,
    bf16* __restrict__ O)
{
    __shared__ bf16 smem[128 * 72];
    bf16* Ks = smem;               // [s][d] rows 0..63, stride 72
    bf16* Vt = smem + 64 * 72;     // [d][s-permuted] rows 0..63, stride 72
    const int tid = threadIdx.x, wave = tid >> 6, lane = tid & 63;
    const int ln = lane & 31, hh = lane >> 5;
    const int hw = blockIdx.x;
    const int bh = (hw & 7) * 8 + ((hw >> 3) & 7);   // XCD c owns bh in [8c,8c+8)
    const int qx = hw >> 6;                          // 0..7 (256-q tile)
    const int b = bh >> 4, head = bh & 15;
    const bf16* __restrict__ Kb  = K  + (size_t)bh * (2112 * 64);
    const bf16* __restrict__ Vtb = VT + (size_t)bh * (64 * 2112);
    const int nkeys = nk[b];
    const int send = ((nkeys + 63) >> 6) << 6;
    const int qg = qx * 256 + wave * 64 + ln;        // qh=0 row; qh=1 adds 32

    bf16x8 qf0[4], qf1[4];
#pragma unroll
    for (int kt = 0; kt < 4; ++kt) {
        qf0[kt] = *(const bf16x8*)&Q[((size_t)bh * 2048 + qg) * 64 + kt * 16 + hh * 8];
        qf1[kt] = *(const bf16x8*)&Q[((size_t)bh * 2048 + qg + 32) * 64 + kt * 16 + hh * 8];
    }

    f32x16 m24;
#pragma unroll
    for (int r = 0; r < 16; ++r) m24[r] = -LOGBIAS;

    float l0 = 0.f, l1 = 0.f;
    f32x16 acc00, acc01, acc10, acc11;
#pragma unroll
    for (int r = 0; r < 16; ++r) {
        acc00[r] = 0.f; acc01[r] = 0.f; acc10[r] = 0.f; acc11[r] = 0.f;
    }

    const int ks_s = tid >> 3, ks_c = (tid & 7) * 8;
    const int vd = tid >> 3, vs = (tid & 7) * 8;

    bf16x8 kr0, kr1, vr0, vr1;
    kr0 = *(const bf16x8*)&Kb[(size_t)ks_s * 64 + ks_c];
    kr1 = *(const bf16x8*)&Kb[(size_t)(ks_s + 32) * 64 + ks_c];
    vr0 = *(const bf16x8*)&Vtb[(size_t)vd * 2112 + vs];
    vr1 = *(const bf16x8*)&Vtb[(size_t)(vd + 32) * 2112 + vs];

    for (int s0 = 0; s0 < send; s0 += 64) {
        __syncthreads();
        *(bf16x8*)&Ks[ks_s * 72 + ks_c]        = kr0;
        *(bf16x8*)&Ks[(ks_s + 32) * 72 + ks_c] = kr1;
        *(bf16x8*)&Vt[vd * 72 + vs]            = vr0;
        *(bf16x8*)&Vt[(vd + 32) * 72 + vs]     = vr1;
        __syncthreads();

        if (s0 + 64 < send) {
            const int sn = s0 + 64;
            kr0 = *(const bf16x8*)&Kb[(size_t)(sn + ks_s) * 64 + ks_c];
            kr1 = *(const bf16x8*)&Kb[(size_t)(sn + ks_s + 32) * 64 + ks_c];
            vr0 = *(const bf16x8*)&Vtb[(size_t)vd * 2112 + sn + vs];
            vr1 = *(const bf16x8*)&Vtb[(size_t)(vd + 32) * 2112 + sn + vs];
        }

        // ---- S^T = K * Q^T for both q-groups; each kf read feeds 2 MFMAs ----
        f32x16 sc0[2], sc1[2];
#pragma unroll
        for (int ts = 0; ts < 2; ++ts) {
            bf16x8 kf = *(const bf16x8*)&Ks[(ts * 32 + ln) * 72 + hh * 8];
            f32x16 sA = MFMA32(kf, qf0[0], m24);   // bias pre-seeded
            f32x16 sB = MFMA32(kf, qf1[0], m24);
#pragma unroll
            for (int kt = 1; kt < 4; ++kt) {
                kf = *(const bf16x8*)&Ks[(ts * 32 + ln) * 72 + kt * 16 + hh * 8];
                sA = MFMA32(kf, qf0[kt], sA);
                sB = MFMA32(kf, qf1[kt], sB);
            }
            sc0[ts] = sA; sc1[ts] = sB;
        }

        // ---- exp2 + pack P into register B-fragments (sigma order) ----
        float rs0 = 0.f, rs1 = 0.f;
        bf16x8 pf0[4], pf1[4];
        if (s0 + 64 <= nkeys) {
#pragma unroll
            for (int ts = 0; ts < 2; ++ts)
#pragma unroll
                for (int rg = 0; rg < 4; ++rg)
#pragma unroll
                    for (int i = 0; i < 4; ++i) {
                        float p0 = __builtin_amdgcn_exp2f(sc0[ts][rg * 4 + i]);
                        float p1 = __builtin_amdgcn_exp2f(sc1[ts][rg * 4 + i]);
                        rs0 += p0; rs1 += p1;
                        pf0[ts * 2 + (rg >> 1)][(rg & 1) * 4 + i] = (bf16)p0;
                        pf1[ts * 2 + (rg >> 1)][(rg & 1) * 4 + i] = (bf16)p1;
                    }
        } else {
#pragma unroll
            for (int ts = 0; ts < 2; ++ts)
#pragma unroll
                for (int rg = 0; rg < 4; ++rg)
#pragma unroll
                    for (int i = 0; i < 4; ++i) {
                        int key = s0 + ts * 32 + rg * 8 + hh * 4 + i;
                        float add = (key < nkeys) ? 0.f : -1e30f;
                        float p0 = __builtin_amdgcn_exp2f(sc0[ts][rg * 4 + i] + add);
                        float p1 = __builtin_amdgcn_exp2f(sc1[ts][rg * 4 + i] + add);
                        rs0 += p0; rs1 += p1;
                        pf0[ts * 2 + (rg >> 1)][(rg & 1) * 4 + i] = (bf16)p0;
                        pf1[ts * 2 + (rg >> 1)][(rg & 1) * 4 + i] = (bf16)p1;
                    }
        }
        l0 += rs0; l1 += rs1;

        // ---- O^T += V^T * P; each Vt read feeds 2 MFMAs ----
#pragma unroll
        for (int st = 0; st < 4; ++st) {
            bf16x8 a0 = *(const bf16x8*)&Vt[ln * 72 + st * 16 + hh * 8];
            acc00 = MFMA32(a0, pf0[st], acc00);
            acc10 = MFMA32(a0, pf1[st], acc10);
            bf16x8 a1 = *(const bf16x8*)&Vt[(32 + ln) * 72 + st * 16 + hh * 8];
            acc01 = MFMA32(a1, pf0[st], acc01);
            acc11 = MFMA32(a1, pf1[st], acc11);
        }
    }

    // ---- epilogue: normalize, transpose via smem scratch, store (2 passes) --
    __syncthreads();                 // all waves done with Ks/Vt
    l0 += __shfl_xor(l0, 32);
    l1 += __shfl_xor(l1, 32);
    const float inv0 = 1.0f / l0, inv1 = 1.0f / l1;
    bf16* scratch = smem + wave * (32 * 72);
    const int orow = lane >> 3, oc = (lane & 7) * 8;
    const int qrow0 = qx * 256 + wave * 64;

    // qh = 0
#pragma unroll
    for (int rg = 0; rg < 4; ++rg) {
        bf16x4 ob;
#pragma unroll
        for (int i = 0; i < 4; ++i) ob[i] = (bf16)(acc00[rg * 4 + i] * inv0);
        *(bf16x4*)&scratch[ln * 72 + rg * 8 + hh * 4] = ob;
#pragma unroll
        for (int i = 0; i < 4; ++i) ob[i] = (bf16)(acc01[rg * 4 + i] * inv0);
        *(bf16x4*)&scratch[ln * 72 + 32 + rg * 8 + hh * 4] = ob;
    }
    __builtin_amdgcn_s_waitcnt(0xC07F);   // lgkmcnt(0)
    __builtin_amdgcn_sched_barrier(0);
#pragma unroll
    for (int pass = 0; pass < 4; ++pass) {
        int ml = pass * 8 + orow;
        bf16x8 ov = *(const bf16x8*)&scratch[ml * 72 + oc];
        *(bf16x8*)&O[((size_t)b * 2048 + qrow0 + ml) * 1024 + head * 64 + oc] = ov;
    }
    __builtin_amdgcn_s_waitcnt(0xC07F);   // reads retired before overwrite
    __builtin_amdgcn_sched_barrier(0);

    // qh = 1
#pragma unroll
    for (int rg = 0; rg < 4; ++rg) {
        bf16x4 ob;
#pragma unroll
        for (int i = 0; i < 4; ++i) ob[i] = (bf16)(acc10[rg * 4 + i] * inv1);
        *(bf16x4*)&scratch[ln * 72 + rg * 8 + hh * 4] = ob;
#pragma unroll
        for (int i = 0; i < 4; ++i) ob[i] = (bf16)(acc11[rg * 4 + i] * inv1);
        *(bf16x4*)&scratch[ln * 72 + 32 + rg * 8 + hh * 4] = ob;
    }
    __builtin_amdgcn_s_waitcnt(0xC07F);
    __builtin_amdgcn_sched_barrier(0);
#pragma unroll
    for (int pass = 0; pass < 4; ++pass) {
        int ml = pass * 8 + orow;
        bf16x8 ov = *(const bf16x8*)&scratch[ml * 72 + oc];
        *(bf16x8*)&O[((size_t)b * 2048 + qrow0 + 32 + ml) * 1024 + head * 64 + oc] = ov;
    }
}

// ---------------------------------------------------------------------------
// Output projection: pipelined 256x128 core; fp32 out + bias.
// ---------------------------------------------------------------------------
__global__ __launch_bounds__(512, 2) void out_proj_gemm(
    const bf16* __restrict__ A, const bf16* __restrict__ W,
    const float* __restrict__ bias, float* __restrict__ out)
{
    __shared__ bf16 lds[49152];
    const int hw = blockIdx.x;
    const int bx = (hw & 7) * 32 + (hw >> 3);
    const int m0 = (bx >> 3) * 256, n0 = (bx & 7) * 128;
    const int tid = threadIdx.x, wave = tid >> 6, lane = tid & 63;
    const int sr8 = lane >> 3;
    const int csw = ((lane & 7) ^ sr8) << 3;

    const bf16* a0 = A + (size_t)(m0 + wave * 8 + sr8) * 1024 + csw;
    const bf16* a1 = a0 + (size_t)64 * 1024;
    const bf16* a2 = a0 + (size_t)128 * 1024;
    const bf16* a3 = a0 + (size_t)192 * 1024;
    const bf16* b0 = W + (size_t)(n0 + wave * 8 + sr8) * 1024 + csw;
    const bf16* b1 = b0 + (size_t)64 * 1024;

    const f32x4 z4 = {0.f, 0.f, 0.f, 0.f};
    f32x4 acc[4][4];
#pragma unroll
    for (int i = 0; i < 4; ++i)
#pragma unroll
        for (int j = 0; j < 4; ++j) acc[i][j] = z4;

    gemm_pipe_256x128(a0, a1, a2, a3, b0, b1, lds, wave, lane, acc);

    const int ln = lane & 15, quad = lane >> 4;
    const int wm = wave >> 1, wn = wave & 1;
#pragma unroll
    for (int ni = 0; ni < 4; ++ni) {
        const int n = n0 + wn * 64 + ni * 16 + ln;
        const float bb = bias[n];
#pragma unroll
        for (int mi = 0; mi < 4; ++mi) {
            int m = m0 + wm * 64 + mi * 16 + quad * 4;
#pragma unroll
            for (int r = 0; r < 4; ++r)
                out[(size_t)(m + r) * 1024 + n] = acc[mi][ni][r] + bb;
        }
    }
}

// ---------------------------------------------------------------------------
extern "C" void kernel_launch(void* const* d_in, const int* in_sizes, int n_in,
                              void* d_out, int out_size, void* d_ws, size_t ws_size,
                              hipStream_t stream)
{
    const float* x    = (const float*)d_in[0];
    const int*   mask = (const int*)d_in[1];
    const float* pk   = (const float*)d_in[2];
    const float* pv   = (const float*)d_in[3];
    const float* Wq   = (const float*)d_in[4];
    const float* bq   = (const float*)d_in[5];
    const float* Wk   = (const float*)d_in[6];
    const float* bk   = (const float*)d_in[7];
    const float* Wv   = (const float*)d_in[8];
    const float* bv   = (const float*)d_in[9];
    const float* Wo   = (const float*)d_in[10];
    const float* bo   = (const float*)d_in[11];
    float* out = (float*)d_out;

    bf16* xb    = (bf16*)d_ws;                   // [8192,1024] bf16
    bf16* wb    = xb + (size_t)8388608;          // 4 x [1024,1024] bf16
    bf16* q_ws  = wb + (size_t)4194304;          // [B,H,T,D]
    bf16* k_ws  = q_ws + (size_t)8388608;        // [B,H,S,D] compacted
    bf16* vt_ws = k_ws + (size_t)8650752;        // [B,H,D,S] compacted V^T (sigma cols)
    int*  ridx  = (int*)(vt_ws + (size_t)8650752);  // [B,T]
    int*  nkv   = ridx + 4 * 2048;                  // [B]
    bf16* a_ws  = xb;   // alias: xb consumed by projections before attn writes

    prep<<<dim3(6404), 256, 0, stream>>>(x, Wq, Wk, Wv, Wo, pk, pv, mask,
                                         xb, wb, k_ws, vt_ws, ridx, nkv);
    proj_gemm<<<dim3(768), 512, 0, stream>>>(xb, wb, bq, bk, bv, ridx, nkv,
                                             q_ws, k_ws, vt_ws);
    attn_kernel<<<dim3(512), 256, 0, stream>>>(q_ws, k_ws, vt_ws, nkv, a_ws);
    out_proj_gemm<<<dim3(256), 512, 0, stream>>>(a_ws, wb + (size_t)3 * 1048576,
                                                 bo, out);
}